// Round 2
// baseline (879.111 us; speedup 1.0000x reference)
//
#include <hip/hip_runtime.h>
#include <hip/hip_bf16.h>

#define D_IN 384
#define D_H  64

typedef __attribute__((ext_vector_type(8))) short short8;
typedef __attribute__((ext_vector_type(4))) float f32x4;

__device__ __forceinline__ unsigned short f2bf(float f){
  unsigned u = __float_as_uint(f);
  u += 0x7fffu + ((u >> 16) & 1u);   // round-to-nearest-even
  return (unsigned short)(u >> 16);
}
__device__ __forceinline__ float bf2f(unsigned short u){
  return __uint_as_float((unsigned)u << 16);
}

// ---- K1: init cnt=0, head=-1 ----
__global__ void k_init(int* cnt, int* head, int N){
  int i = blockIdx.x * blockDim.x + threadIdx.x;
  if (i < N) cnt[i] = 0;
  if (i < 4 * N) head[i] = -1;
}

// ---- K2: one pass over edges: degree count + linked-list build ----
// rec[e] = {src, prev-edge-in-chain}; write at index e is fully coalesced.
__global__ void k_build(const int* __restrict__ ei, int* cnt, int* head,
                        int2* __restrict__ rec, int E){
  int e = blockIdx.x * blockDim.x + threadIdx.x;
  if (e >= E) return;
  int s = ei[e];
  int d = ei[E + e];
  atomicAdd(&cnt[d], 1);
  int prev = atomicExch(&head[d * 4 + (e & 3)], e);
  rec[e] = make_int2(s, prev);
}

// ---- K3: dis = rsqrt(deg+1) ----
__global__ void k_dis(const int* __restrict__ cnt, float* __restrict__ dis, int N){
  int i = blockIdx.x * blockDim.x + threadIdx.x;
  if (i < N) dis[i] = rsqrtf((float)(cnt[i] + 1));
}

// ---- K4: hb = bf16( (x @ W_gcn) * dis[row] )  -- pre-scaled by dis[src] ----
__global__ __launch_bounds__(256) void k_gemm(const float* __restrict__ x,
                                              const float* __restrict__ W,
                                              const float* __restrict__ dis,
                                              unsigned short* __restrict__ hb, int N){
  __shared__ __align__(16) short a_sw[4 * 4 * 64 * 8];  // 16 KiB
  __shared__ __align__(16) short b_sw[4 * 4 * 64 * 8];  // 16 KiB
  const int t = threadIdx.x;
  const int node0 = blockIdx.x * 64;
  const int w = t >> 6;     // wave id = m-tile
  const int l = t & 63;     // lane

  f32x4 acc[4];
  #pragma unroll
  for (int nt = 0; nt < 4; nt++) acc[nt] = (f32x4){0.f, 0.f, 0.f, 0.f};

  for (int c = 0; c < 3; c++){
    const int kbase = c * 128;
    #pragma unroll
    for (int r = 0; r < 4; r++){
      int id  = t + 256 * r;        // 0..1023
      int cl  = id & 63;
      int s   = (id >> 6) & 3;      // k-step within chunk
      int tl  = id >> 8;            // m-tile (A) / n-tile (B)
      int k   = kbase + s * 32 + ((cl >> 4) << 3);
      // A cell: x[node0 + tl*16 + (cl&15)][k..k+7]
      {
        int node = node0 + tl * 16 + (cl & 15);
        uint4 pv;
        if (node < N){
          const float* xp = &x[(size_t)node * D_IN + k];
          float4 u0 = *(const float4*)xp;
          float4 u1 = *(const float4*)(xp + 4);
          pv.x = (unsigned)f2bf(u0.x) | ((unsigned)f2bf(u0.y) << 16);
          pv.y = (unsigned)f2bf(u0.z) | ((unsigned)f2bf(u0.w) << 16);
          pv.z = (unsigned)f2bf(u1.x) | ((unsigned)f2bf(u1.y) << 16);
          pv.w = (unsigned)f2bf(u1.z) | ((unsigned)f2bf(u1.w) << 16);
        } else {
          pv.x = pv.y = pv.z = pv.w = 0u;
        }
        *reinterpret_cast<uint4*>(&a_sw[id * 8]) = pv;
      }
      // B cell: W[k..k+7][tl*16 + (cl&15)] (stride 64 floats along k)
      {
        int n = tl * 16 + (cl & 15);
        const float* wp = &W[(size_t)k * D_H + n];
        uint4 qv;
        qv.x = (unsigned)f2bf(wp[0])   | ((unsigned)f2bf(wp[64])  << 16);
        qv.y = (unsigned)f2bf(wp[128]) | ((unsigned)f2bf(wp[192]) << 16);
        qv.z = (unsigned)f2bf(wp[256]) | ((unsigned)f2bf(wp[320]) << 16);
        qv.w = (unsigned)f2bf(wp[384]) | ((unsigned)f2bf(wp[448]) << 16);
        *reinterpret_cast<uint4*>(&b_sw[id * 8]) = qv;
      }
    }
    __syncthreads();
    #pragma unroll
    for (int s = 0; s < 4; s++){
      short8 a = *reinterpret_cast<const short8*>(&a_sw[((w * 4 + s) * 64 + l) * 8]);
      #pragma unroll
      for (int nt = 0; nt < 4; nt++){
        short8 b = *reinterpret_cast<const short8*>(&b_sw[((nt * 4 + s) * 64 + l) * 8]);
        acc[nt] = __builtin_amdgcn_mfma_f32_16x16x32_bf16(a, b, acc[nt], 0, 0, 0);
      }
    }
    __syncthreads();
  }
  // epilogue: C/D layout col = lane&15, row = (lane>>4)*4 + reg; scale by dis[node]
  const int qd = l >> 4;
  const int col0 = l & 15;
  #pragma unroll
  for (int r = 0; r < 4; r++){
    int node = node0 + w * 16 + qd * 4 + r;
    if (node < N){
      float scale = dis[node];
      #pragma unroll
      for (int nt = 0; nt < 4; nt++)
        hb[(size_t)node * D_H + nt * 16 + col0] = f2bf(acc[nt][r] * scale);
    }
  }
}

// ---- K5: aggregation via 4-way linked-list chase (wave per node, lane = feature)
// message already pre-scaled by dis[src]; factor dis[dst] out of the sum.
__global__ void k_agg(const unsigned short* __restrict__ hb,
                      const int2* __restrict__ rec, const int* __restrict__ head,
                      const float* __restrict__ dis, const float* __restrict__ bg,
                      float* __restrict__ hout, int N){
  int gid = blockIdx.x * blockDim.x + threadIdx.x;
  int i = gid >> 6;
  int f = gid & 63;
  if (i >= N) return;
  float dii = dis[i];
  float acc = bf2f(hb[(size_t)i * D_H + f]);   // self-loop: h[i]*dis[i], *dii later
  int c0 = head[i * 4 + 0];
  int c1 = head[i * 4 + 1];
  int c2 = head[i * 4 + 2];
  int c3 = head[i * 4 + 3];
  while ((c0 & c1 & c2 & c3) != -1){
    if (c0 >= 0){ int2 r = rec[c0]; acc += bf2f(hb[(size_t)r.x * D_H + f]); c0 = r.y; }
    if (c1 >= 0){ int2 r = rec[c1]; acc += bf2f(hb[(size_t)r.x * D_H + f]); c1 = r.y; }
    if (c2 >= 0){ int2 r = rec[c2]; acc += bf2f(hb[(size_t)r.x * D_H + f]); c2 = r.y; }
    if (c3 >= 0){ int2 r = rec[c3]; acc += bf2f(hb[(size_t)r.x * D_H + f]); c3 = r.y; }
  }
  float v = acc * dii + bg[f];
  hout[(size_t)i * D_H + f] = v > 0.f ? v : 0.f;
}

// ---- K6: pool (sorted batch -> binary search range) + classifier ----
__global__ void k_pool(const float* __restrict__ hout, const int* __restrict__ batch,
                       const float* __restrict__ wc, const float* __restrict__ bc,
                       float* __restrict__ out, int N, int G){
  int g = blockIdx.x;
  int t = threadIdx.x;
  int lo = 0, hi = N;
  while (lo < hi){ int m = (lo + hi) >> 1; if (batch[m] < g) lo = m + 1; else hi = m; }
  int start = lo;
  lo = start; hi = N;
  while (lo < hi){ int m = (lo + hi) >> 1; if (batch[m] < g + 1) lo = m + 1; else hi = m; }
  int end = lo;

  int f = t & 63;
  int r = t >> 6;
  float sum = 0.f;
  for (int i = start + r; i < end; i += 4) sum += hout[(size_t)i * D_H + f];
  __shared__ float red[256];
  red[t] = sum;
  __syncthreads();
  if (t < 64){
    float z = red[t] + red[t + 64] + red[t + 128] + red[t + 192];
    float p = z * wc[t];
    #pragma unroll
    for (int off = 32; off > 0; off >>= 1) p += __shfl_down(p, off);
    if (t == 0) out[g] = p + bc[0];
  }
}

extern "C" void kernel_launch(void* const* d_in, const int* in_sizes, int n_in,
                              void* d_out, int out_size, void* d_ws, size_t ws_size,
                              hipStream_t stream){
  const float* x     = (const float*)d_in[0];
  const int*   ei    = (const int*)d_in[1];    // [2,E] flat: [0..E)=src, [E..2E)=dst
  const int*   batch = (const int*)d_in[2];
  const float* Wg    = (const float*)d_in[3];
  const float* bg    = (const float*)d_in[4];
  const float* wc    = (const float*)d_in[5];
  const float* bc    = (const float*)d_in[6];
  float* out = (float*)d_out;

  const int N = in_sizes[2];
  const int E = in_sizes[1] / 2;
  const int G = out_size;

  char* ws = (char*)d_ws;
  size_t off = 0;
  auto alloc = [&](size_t bytes) -> void* {
    void* p = ws + off;
    off += (bytes + 255) & ~(size_t)255;
    return p;
  };
  int*            cnt  = (int*)           alloc((size_t)N * 4);
  float*          dis  = (float*)         alloc((size_t)N * 4);
  int*            head = (int*)           alloc((size_t)N * 4 * 4);
  int2*           rec  = (int2*)          alloc((size_t)E * 8);
  unsigned short* hb   = (unsigned short*)alloc((size_t)N * D_H * 2);
  float*          hout = (float*)         alloc((size_t)N * D_H * 4);

  k_init <<<(4 * N + 255) / 256, 256, 0, stream>>>(cnt, head, N);
  k_build<<<(E + 255) / 256, 256, 0, stream>>>(ei, cnt, head, rec, E);
  k_dis  <<<(N + 255) / 256, 256, 0, stream>>>(cnt, dis, N);
  k_gemm <<<(N + 63) / 64, 256, 0, stream>>>(x, Wg, dis, hb, N);
  k_agg  <<<(N + 3) / 4, 256, 0, stream>>>(hb, rec, head, dis, bg, hout, N);
  k_pool <<<G, 256, 0, stream>>>(hout, batch, wc, bc, out, N, G);
}